// Round 8
// baseline (671.322 us; speedup 1.0000x reference)
//
#include <hip/hip_runtime.h>
#include <math.h>

// Problem constants
// N=64, C=64 (=Cout), T=256, V=25, S=3, inter=16
// x: [N,C,T,V] fp32;  out: [N,C,T,V] fp32

typedef __attribute__((ext_vector_type(8))) __bf16 bf16x8;
typedef __attribute__((ext_vector_type(4))) float  f32x4;

#define AIF_HALF 196608   // bf16 elements in hi (and in lo) fragment tensor

// ---------------------------------------------------------------------------
// Kernel A (unchanged from R7): grid = 1024 blocks (n*16 + tt), 4 waves.
// ---------------------------------------------------------------------------
__global__ __launch_bounds__(256, 3) void gcn_kA(const float* __restrict__ x,
                                                 const float* __restrict__ Wa,
                                                 const float* __restrict__ ba,
                                                 const float* __restrict__ Wb,
                                                 const float* __restrict__ bb,
                                                 float* __restrict__ Pws) {
    const int bid = blockIdx.x;      // n*16 + tt
    const int n  = bid >> 4;
    const int tt = bid & 15;
    const int tid  = threadIdx.x;
    const int lane = tid & 63;
    const int wv   = tid >> 6;
    const int col  = lane & 15;
    const int quad = lane >> 4;

    __shared__ __align__(16) __bf16 xB[112 * 72];      // [q][c]  16,128 B
    __shared__ __align__(16) __bf16 aT[3][32 * 72];    // [s][v][k] 13,824 B
    __shared__ __align__(16) __bf16 bT[3][32 * 72];    // [s][v][k] 13,824 B

    for (int j = tid; j < 12 * 72; j += 256) xB[100 * 72 + j] = (__bf16)0.f;
    for (int j = tid; j < 7 * 72; j += 256) {
        #pragma unroll
        for (int s = 0; s < 3; ++s) {
            aT[s][25 * 72 + j] = (__bf16)0.f;
            bT[s][25 * 72 + j] = (__bf16)0.f;
        }
    }

    bf16x8 waf0[3], waf1[3], wbf0[3], wbf1[3];
    float ba4[3][4], bb4[3][4];
    #pragma unroll
    for (int s = 0; s < 3; ++s) {
        const float* wap = Wa + (size_t)s * 1024 + col * 64 + quad * 8;
        const float* wbp = Wb + (size_t)s * 1024 + col * 64 + quad * 8;
        #pragma unroll
        for (int j = 0; j < 8; ++j) { waf0[s][j] = (__bf16)wap[j];      wbf0[s][j] = (__bf16)wbp[j]; }
        #pragma unroll
        for (int j = 0; j < 8; ++j) { waf1[s][j] = (__bf16)wap[32 + j]; wbf1[s][j] = (__bf16)wbp[32 + j]; }
        #pragma unroll
        for (int r = 0; r < 4; ++r) {
            ba4[s][r] = ba[s * 16 + quad * 4 + r];
            bb4[s][r] = bb[s * 16 + quad * 4 + r];
        }
    }

    f32x4 pacc[3];
    #pragma unroll
    for (int s = 0; s < 3; ++s) pacc[s] = (f32x4){0.f, 0.f, 0.f, 0.f};
    const int mi = wv >> 1, ni = wv & 1;

    const float* xbase = x + (size_t)n * 409600 + tt * 400;

    for (int cc = 0; cc < 4; ++cc) {
        __syncthreads();
        const float* xc = xbase + cc * 100;
        #pragma unroll
        for (int it = 0; it < 7; ++it) {
            int j4 = tid + it * 256;
            if (j4 < 1600) {
                int c  = j4 / 25;
                int qq = (j4 - c * 25) * 4;
                float4 xv = *(const float4*)(xc + c * 6400 + qq);
                __bf16* dst = &xB[qq * 72 + c];
                dst[0]   = (__bf16)xv.x;
                dst[72]  = (__bf16)xv.y;
                dst[144] = (__bf16)xv.z;
                dst[216] = (__bf16)xv.w;
            }
        }
        __syncthreads();

        #pragma unroll
        for (int s = 0; s < 3; ++s) {
            for (int jt = wv; jt < 7; jt += 4) {
                int q = jt * 16 + col;
                const __bf16* bp = &xB[q * 72 + quad * 8];
                bf16x8 b0 = *(const bf16x8*)bp;
                bf16x8 b1 = *(const bf16x8*)(bp + 32);
                f32x4 da = {0.f, 0.f, 0.f, 0.f}, db = {0.f, 0.f, 0.f, 0.f};
                da = __builtin_amdgcn_mfma_f32_16x16x32_bf16(waf0[s], b0, da, 0, 0, 0);
                da = __builtin_amdgcn_mfma_f32_16x16x32_bf16(waf1[s], b1, da, 0, 0, 0);
                db = __builtin_amdgcn_mfma_f32_16x16x32_bf16(wbf0[s], b0, db, 0, 0, 0);
                db = __builtin_amdgcn_mfma_f32_16x16x32_bf16(wbf1[s], b1, db, 0, 0, 0);
                if (q < 100) {
                    int tl = q / 25, v = q - tl * 25;
                    #pragma unroll
                    for (int r = 0; r < 4; ++r) {
                        int k = (quad * 4 + r) * 4 + tl;   // i*4 + tl
                        aT[s][v * 72 + k] = (__bf16)(da[r] + ba4[s][r]);
                        bT[s][v * 72 + k] = (__bf16)(db[r] + bb4[s][r]);
                    }
                }
            }
        }
        __syncthreads();

        #pragma unroll
        for (int s = 0; s < 3; ++s) {
            #pragma unroll
            for (int k0 = 0; k0 < 64; k0 += 32) {
                bf16x8 af  = *(const bf16x8*)&aT[s][(mi * 16 + col) * 72 + k0 + quad * 8];
                bf16x8 bfr = *(const bf16x8*)&bT[s][(ni * 16 + col) * 72 + k0 + quad * 8];
                pacc[s] = __builtin_amdgcn_mfma_f32_16x16x32_bf16(af, bfr, pacc[s], 0, 0, 0);
            }
        }
    }

    #pragma unroll
    for (int s = 0; s < 3; ++s) {
        #pragma unroll
        for (int r = 0; r < 4; ++r) {
            int v = mi * 16 + quad * 4 + r;
            int w = ni * 16 + col;
            if (v < 25 && w < 25)
                atomicAdd(&Pws[(size_t)(s * 64 + n) * 625 + v * 25 + w], pacc[s][r]);
        }
    }
}

// ---------------------------------------------------------------------------
// Kernel B (unchanged from R9): Ai in MFMA B-fragment layout, bf16 hi+lo.
// ---------------------------------------------------------------------------
__global__ __launch_bounds__(256) void gcn_kB(const float* __restrict__ Pws,
                                              const float* __restrict__ PA,
                                              const float* __restrict__ alpha,
                                              __bf16* __restrict__ aiF) {
    int j = blockIdx.x * 256 + threadIdx.x;
    if (j < 120000) {
        int sn = j / 625;
        int r  = j - sn * 625;
        int s  = sn >> 6;
        float val = PA[s * 625 + r] + alpha[0] * tanhf(Pws[j] * (1.f / 4096.f));
        int k  = r / 25;
        int nn = r - k * 25;
        int vt = nn >> 4, colx = nn & 15;
        int idx = ((sn * 2 + vt) << 9) + (colx << 5) + k;
        __bf16 h = (__bf16)val;
        aiF[idx]            = h;
        aiF[AIF_HALF + idx] = (__bf16)(val - (float)h);
    }
}

// ---------------------------------------------------------------------------
// Kernel C (R10: wave-banded staging + retained-register residual +
// wave-private LDS epilogue transpose -> fully coalesced float4 y1 stores):
//   per (n, tt) block, 4 chunks of 4 t:
//     stage: wave wv loads ITS 16-c band as float4 (retained in xv[7]) ->
//            bf16 into shared xB[q][c]  (union over 4 waves = all 64 c)
//     s-loop: u_s = Wd[s]@x (MFMA) -> uLw (wave-private);
//             acc += uLw x Ai_s (MFMA, Ai bf16 hi+lo)  [unchanged math]
//     epilogue: BN(acc) -> ySw (per-wave, aliases uLw; wave-private, no bar);
//               read ySw as float4 + retained xv residual + relu ->
//               y1 float4 (full sectors); msA[7] register accumulators.
//   end: msA -> LDS reduce (xB scratch) -> meanT atomics.
//   Still 2 barriers/chunk. LDS = 16,128 + 26,624 = 42,752 B.
// ---------------------------------------------------------------------------
__global__ __launch_bounds__(256, 3) void gcn_kC(const float* __restrict__ x,
                                              const __bf16* __restrict__ aiF,
                                              const float* __restrict__ Wd,
                                              const float* __restrict__ bd,
                                              const float* __restrict__ gamma,
                                              const float* __restrict__ beta,
                                              float* __restrict__ y1,
                                              float* __restrict__ meanT) {
    const int bid = blockIdx.x;
    const int tt = bid & 15;
    const int n  = bid >> 4;
    const int tid  = threadIdx.x;
    const int lane = tid & 63;
    const int wv   = tid >> 6;
    const int col  = lane & 15;
    const int quad = lane >> 4;

    __shared__ __align__(16) __bf16 xB[112 * 72];           // 16,128 B
    // per-wave union region (6,656 B each):
    //   uL view: 64 rows x 40 bf16 (80 B row stride, first 5,120 B)
    //   yS view: 16 rows x 104 f32 (416 B row stride, all 6,656 B)
    __shared__ __align__(16) unsigned char uY[4 * 6656];    // 26,624 B

    __bf16* uLw = (__bf16*)(uY + wv * 6656);
    float*  ySw = (float*) (uY + wv * 6656);

    // init: xB pad rows; uLw pad cols 25..31 (read by agg MFMA quad-3 frag)
    for (int j = tid; j < 12 * 72; j += 256) xB[100 * 72 + j] = (__bf16)0.f;
    {
        __bf16* rz = uLw + lane * 40;
        #pragma unroll
        for (int k = 25; k < 32; ++k) rz[k] = (__bf16)0.f;
    }

    // Ai B-fragments: coalesced b128 loads from fragment tensor (12 loads)
    bf16x8 aiH[3][2], aiL[3][2];
    #pragma unroll
    for (int s = 0; s < 3; ++s) {
        #pragma unroll
        for (int vt = 0; vt < 2; ++vt) {
            const __bf16* p = aiF + ((size_t)((s * 64 + n) * 2 + vt)) * 512
                                  + col * 32 + quad * 8;
            aiH[s][vt] = *(const bf16x8*)p;
            aiL[s][vt] = *(const bf16x8*)(p + AIF_HALF);
        }
    }

    // Wd A-fragments: A[m=o=wv*16+col][k=c]
    bf16x8 wd0[3], wd1[3];
    #pragma unroll
    for (int s = 0; s < 3; ++s) {
        const float* wdp = Wd + (size_t)(s * 64 + wv * 16 + col) * 64 + quad * 8;
        #pragma unroll
        for (int j = 0; j < 8; ++j) wd0[s][j] = (__bf16)wdp[j];
        #pragma unroll
        for (int j = 0; j < 8; ++j) wd1[s][j] = (__bf16)wdp[32 + j];
    }

    // epilogue constants, per ml (o = wv*16 + ml*4 + quad)
    float scv[4], btv[4], bdsv[4];
    #pragma unroll
    for (int ml = 0; ml < 4; ++ml) {
        int o = wv * 16 + ml * 4 + quad;
        scv[ml]  = gamma[o] * rsqrtf(1.f + 1e-5f);
        btv[ml]  = beta[o];
        bdsv[ml] = bd[o] + bd[64 + o] + bd[128 + o];
    }

    // per-thread meanT accumulators (static indexing)
    f32x4 msA[7];
    #pragma unroll
    for (int it = 0; it < 7; ++it) msA[it] = (f32x4){0.f, 0.f, 0.f, 0.f};

    // wave's c-band base pointers
    const float* xgw = x  + (size_t)(n * 64 + wv * 16) * 6400 + tt * 400;
    float*       ygw = y1 + (size_t)(n * 64 + wv * 16) * 6400 + tt * 400;

    for (int cc = 0; cc < 4; ++cc) {
        f32x4 acc[4][2];
        #pragma unroll
        for (int ml = 0; ml < 4; ++ml) {
            acc[ml][0] = (f32x4){0.f, 0.f, 0.f, 0.f};
            acc[ml][1] = (f32x4){0.f, 0.f, 0.f, 0.f};
        }

        __syncthreads();   // all waves done reading xB from prev chunk
        // stage: wave wv loads its own 16-c band; retain fp32 in xv[]
        const float* xc = xgw + cc * 100;
        float4 xv[7];
        #pragma unroll
        for (int it = 0; it < 7; ++it) {
            int j = lane + it * 64;
            if (j < 400) {
                int cl = j / 25;               // 0..15
                int qq = (j - cl * 25) * 4;    // 0..96
                xv[it] = *(const float4*)(xc + cl * 6400 + qq);
                int c = wv * 16 + cl;
                __bf16* dst = &xB[qq * 72 + c];
                dst[0]   = (__bf16)xv[it].x;
                dst[72]  = (__bf16)xv[it].y;
                dst[144] = (__bf16)xv[it].z;
                dst[216] = (__bf16)xv[it].w;
            }
        }
        __syncthreads();

        #pragma unroll
        for (int s = 0; s < 3; ++s) {
            // u MFMA: wave wv owns o-tile wv; 7 q-tiles of 16 (uLw wave-private)
            #pragma unroll
            for (int qt = 0; qt < 7; ++qt) {
                const __bf16* bp = &xB[(qt * 16 + col) * 72 + quad * 8];
                bf16x8 b0 = *(const bf16x8*)bp;
                bf16x8 b1 = *(const bf16x8*)(bp + 32);
                f32x4 u = {0.f, 0.f, 0.f, 0.f};
                u = __builtin_amdgcn_mfma_f32_16x16x32_bf16(wd0[s], b0, u, 0, 0, 0);
                u = __builtin_amdgcn_mfma_f32_16x16x32_bf16(wd1[s], b1, u, 0, 0, 0);
                int q = qt * 16 + col;       // D col
                if (q < 100) {
                    int trel = q / 25, v = q - trel * 25;
                    int rowbase = (quad * 16 + trel) * 40 + v;   // row (quad*4+r)*4+trel
                    uLw[rowbase]       = (__bf16)u[0];
                    uLw[rowbase + 160] = (__bf16)u[1];
                    uLw[rowbase + 320] = (__bf16)u[2];
                    uLw[rowbase + 480] = (__bf16)u[3];
                }
            }
            // aggregation MFMA: same wave's uLw rows; no barrier
            #pragma unroll
            for (int ml = 0; ml < 4; ++ml) {
                bf16x8 af = *(const bf16x8*)&uLw[(ml * 16 + col) * 40 + quad * 8];
                acc[ml][0] = __builtin_amdgcn_mfma_f32_16x16x32_bf16(af, aiH[s][0], acc[ml][0], 0, 0, 0);
                acc[ml][1] = __builtin_amdgcn_mfma_f32_16x16x32_bf16(af, aiH[s][1], acc[ml][1], 0, 0, 0);
                acc[ml][0] = __builtin_amdgcn_mfma_f32_16x16x32_bf16(af, aiL[s][0], acc[ml][0], 0, 0, 0);
                acc[ml][1] = __builtin_amdgcn_mfma_f32_16x16x32_bf16(af, aiL[s][1], acc[ml][1], 0, 0, 0);
            }
        }

        // phase 1: BN -> ySw (wave-private; aliases uLw, dead after agg)
        #pragma unroll
        for (int ml = 0; ml < 4; ++ml) {
            int ol = ml * 4 + quad;
            #pragma unroll
            for (int vt = 0; vt < 2; ++vt) {
                int v = vt * 16 + col;
                if (v < 25) {
                    #pragma unroll
                    for (int r = 0; r < 4; ++r)
                        ySw[ol * 104 + r * 25 + v] =
                            scv[ml] * (acc[ml][vt][r] + bdsv[ml]) + btv[ml];
                }
            }
        }

        // phase 2 (same wave): ySw + retained xv residual -> relu -> float4 y1
        float* yc2 = ygw + cc * 100;
        #pragma unroll
        for (int it = 0; it < 7; ++it) {
            int j = lane + it * 64;
            if (j < 400) {
                int cl = j / 25;
                int qq = (j - cl * 25) * 4;
                f32x4 yv = *(const f32x4*)&ySw[cl * 104 + qq];
                float4 o4;
                o4.x = yv[0] + xv[it].x; o4.x = o4.x > 0.f ? o4.x : 0.f;
                o4.y = yv[1] + xv[it].y; o4.y = o4.y > 0.f ? o4.y : 0.f;
                o4.z = yv[2] + xv[it].z; o4.z = o4.z > 0.f ? o4.z : 0.f;
                o4.w = yv[3] + xv[it].w; o4.w = o4.w > 0.f ? o4.w : 0.f;
                *(float4*)(yc2 + cl * 6400 + qq) = o4;
                msA[it][0] += o4.x;
                msA[it][1] += o4.y;
                msA[it][2] += o4.z;
                msA[it][3] += o4.w;
            }
        }

        // re-zero uLw pad cols (clobbered by ySw; needed by next chunk's agg)
        {
            __bf16* rz = uLw + lane * 40;
            #pragma unroll
            for (int k = 25; k < 32; ++k) rz[k] = (__bf16)0.f;
        }
    }

    // meanT: per-wave LDS reduce in xB scratch, then global atomics
    __syncthreads();                       // all waves done with xB MFMA reads
    float* msW = (float*)xB + wv * 1008;   // 400 used per wave (4032 total fits)
    for (int j2 = lane; j2 < 400; j2 += 64) msW[j2] = 0.f;
    #pragma unroll
    for (int it = 0; it < 7; ++it) {
        int j = lane + it * 64;
        if (j < 400) {
            int cl = j / 25;
            int qq = (j - cl * 25) * 4;
            #pragma unroll
            for (int k = 0; k < 4; ++k) {
                int q = qq + k;
                int v = q >= 75 ? q - 75 : (q >= 50 ? q - 50 : (q >= 25 ? q - 25 : q));
                atomicAdd(&msW[cl * 25 + v], msA[it][k]);
            }
        }
    }
    for (int j2 = lane; j2 < 400; j2 += 64) {
        int cl = j2 / 25, v = j2 - cl * 25;
        atomicAdd(&meanT[(n * 64 + wv * 16 + cl) * 25 + v], msW[j2]);
    }
}

// ---------------------------------------------------------------------------
// Kernel D: spatial SE gate.  g2p[n][v] = 1 + sigmoid(conv_V(meanT/T, Wsa)+bsa)
// ---------------------------------------------------------------------------
__global__ __launch_bounds__(256) void gcn_kD(const float* __restrict__ meanT,
                                              const float* __restrict__ Wsa,
                                              const float* __restrict__ bsa,
                                              float* __restrict__ g2p) {
    const int n = blockIdx.x;
    const int tid = threadIdx.x;
    __shared__ float sm[1600], wl[1600];
    for (int j = tid; j < 1600; j += 256) {
        sm[j] = meanT[n * 1600 + j] * (1.f / 256.f);
        wl[j] = Wsa[j];
    }
    __syncthreads();
    if (tid < 25) {
        float acc = bsa[0];
        for (int c = 0; c < 64; ++c) {
            #pragma unroll
            for (int k = 0; k < 25; ++k) {
                int j = tid + k - 12;
                if (j >= 0 && j < 25) acc += sm[c * 25 + j] * wl[c * 25 + k];
            }
        }
        g2p[n * 25 + tid] = 1.f + 1.f / (1.f + expf(-acc));
    }
}

// ---------------------------------------------------------------------------
// Kernel E: M2[n][c][t] = (1/V) sum_v y1 * g2p[n][v]  (float4 staging)
// ---------------------------------------------------------------------------
__global__ __launch_bounds__(256) void gcn_kE(const float* __restrict__ y1,
                                              const float* __restrict__ g2p,
                                              float* __restrict__ M2) {
    const int bid = blockIdx.x;     // n*64 + c
    const int n = bid >> 6;
    const int tid = threadIdx.x;
    __shared__ float yl[6400];
    __shared__ float g2l[25];
    const float4* yp = (const float4*)(y1 + (size_t)bid * 6400);
    float4* ylv = (float4*)yl;
    for (int j = tid; j < 1600; j += 256) ylv[j] = yp[j];
    if (tid < 25) g2l[tid] = g2p[n * 25 + tid];
    __syncthreads();
    float sum = 0.f;
    #pragma unroll
    for (int v = 0; v < 25; ++v) sum += yl[tid * 25 + v] * g2l[v];
    M2[bid * 256 + tid] = sum * 0.04f;
}

// ---------------------------------------------------------------------------
// Kernel FG (merge of kF+kG): per n, stage M2[n] in LDS once, then
//   g3[t] = 1 + sigmoid(conv_T(M2, Wta)+bta)
//   M3[c] = (1/T) sum_t M2[c][t]*g3[t];  MLP -> g4[c] = 1+sigmoid
// ---------------------------------------------------------------------------
__global__ __launch_bounds__(256) void gcn_kFG(const float* __restrict__ M2,
                                               const float* __restrict__ Wta,
                                               const float* __restrict__ bta,
                                               const float* __restrict__ W1,
                                               const float* __restrict__ b1,
                                               const float* __restrict__ W2,
                                               const float* __restrict__ b2,
                                               float* __restrict__ g3p,
                                               float* __restrict__ g4p) {
    const int n = blockIdx.x;
    const int tid = threadIdx.x;
    __shared__ float m2L[64 * 260];   // [c][t], pad 260
    __shared__ float wl[576];
    __shared__ float g3l[256], part[256], M3[64], h[32];

    for (int j = tid; j < 16384; j += 256) {
        int c = j >> 8, t = j & 255;
        m2L[c * 260 + t] = M2[(size_t)n * 16384 + j];
    }
    for (int j = tid; j < 576; j += 256) wl[j] = Wta[j];
    __syncthreads();

    // phase F: temporal conv (kernel 9, pad 4), t = tid
    {
        const int t = tid;
        float acc = bta[0];
        for (int c = 0; c < 64; ++c) {
            const float* mp = &m2L[c * 260];
            #pragma unroll
            for (int k = 0; k < 9; ++k) {
                int j = t + k - 4;
                if (j >= 0 && j < 256) acc += mp[j] * wl[c * 9 + k];
            }
        }
        float g3 = 1.f + 1.f / (1.f + expf(-acc));
        g3l[t] = g3;
        g3p[n * 256 + t] = g3;
    }
    __syncthreads();

    // phase G: channel SE
    {
        const int c = tid >> 2, q = tid & 3;
        float p = 0.f;
        const float* mp = &m2L[c * 260 + q * 64];
        #pragma unroll 16
        for (int j = 0; j < 64; ++j) p += mp[j] * g3l[q * 64 + j];
        part[tid] = p;
    }
    __syncthreads();
    if (tid < 64)
        M3[tid] = (part[tid * 4] + part[tid * 4 + 1] + part[tid * 4 + 2] +
                   part[tid * 4 + 3]) * (1.f / 256.f);
    __syncthreads();
    if (tid < 32) {
        float acc = b1[tid];
        #pragma unroll 16
        for (int cc = 0; cc < 64; ++cc) acc += W1[tid * 64 + cc] * M3[cc];
        h[tid] = acc > 0.f ? acc : 0.f;
    }
    __syncthreads();
    if (tid < 64) {
        float acc = b2[tid];
        #pragma unroll
        for (int j = 0; j < 32; ++j) acc += W2[tid * 32 + j] * h[j];
        g4p[n * 64 + tid] = 1.f + 1.f / (1.f + expf(-acc));
    }
}

// ---------------------------------------------------------------------------
// Kernel H: final gating, in place:  y = y1 * g2p[v] * g3p[t] * g4p[c]
// ---------------------------------------------------------------------------
__global__ __launch_bounds__(256) void gcn_kH(float* __restrict__ y,
                                              const float* __restrict__ g2p,
                                              const float* __restrict__ g3p,
                                              const float* __restrict__ g4p) {
    const int bid = blockIdx.x;  // n*64 + c
    const int n = bid >> 6;
    const int tid = threadIdx.x;
    __shared__ float g3l[256], g2l[25];
    g3l[tid] = g3p[n * 256 + tid];
    if (tid < 25) g2l[tid] = g2p[n * 25 + tid];
    const float g4 = g4p[bid];
    __syncthreads();
    float4* yp = (float4*)(y + (size_t)bid * 6400);
    for (int f = tid; f < 1600; f += 256) {
        float4 val = yp[f];
        float* vv = (float*)&val;
        const int base = f * 4;
        #pragma unroll
        for (int k = 0; k < 4; ++k) {
            int idx = base + k;
            int t = (int)(((unsigned long long)idx * 1374389535ull) >> 35);
            int v = idx - t * 25;
            vv[k] *= g2l[v] * g3l[t] * g4;
        }
        yp[f] = val;
    }
}

// ---------------------------------------------------------------------------
extern "C" void kernel_launch(void* const* d_in, const int* in_sizes, int n_in,
                              void* d_out, int out_size, void* d_ws, size_t ws_size,
                              hipStream_t stream) {
    const float* x     = (const float*)d_in[0];
    const float* PA    = (const float*)d_in[1];
    const float* alpha = (const float*)d_in[2];
    const float* Wa    = (const float*)d_in[3];
    const float* ba    = (const float*)d_in[4];
    const float* Wb    = (const float*)d_in[5];
    const float* bb    = (const float*)d_in[6];
    const float* Wd    = (const float*)d_in[7];
    const float* bd    = (const float*)d_in[8];
    const float* gamma = (const float*)d_in[9];
    const float* beta  = (const float*)d_in[10];
    const float* Wsa   = (const float*)d_in[11];
    const float* bsa   = (const float*)d_in[12];
    const float* Wta   = (const float*)d_in[13];
    const float* bta   = (const float*)d_in[14];
    const float* W1    = (const float*)d_in[15];
    const float* b1    = (const float*)d_in[16];
    const float* W2    = (const float*)d_in[17];
    const float* b2    = (const float*)d_in[18];

    float* out = (float*)d_out;
    float* ws  = (float*)d_ws;

    // workspace layout (floats)
    float*  Pws   = ws;                        // 120000  (zeroed; kA atomics)
    float*  meanT = ws + 120000;               // 102400  (zeroed; kC atomics)
    __bf16* aiF   = (__bf16*)(ws + 222400);    // 393216 bf16 = 196608 f (zeroed pads)
    float*  M2    = ws + 419008;               // 4194304
    float*  g2p   = ws + 4613312;              // 1600
    float*  g3p   = ws + 4614912;              // 16384
    float*  g4p   = ws + 4631296;              // 4096

    hipMemsetAsync(ws, 0, 222400 * sizeof(float), stream);   // Pws + meanT
    hipMemsetAsync(aiF, 0, 786432, stream);                  // aiF (incl. pads)

    gcn_kA<<<1024, 256, 0, stream>>>(x, Wa, ba, Wb, bb, Pws);
    gcn_kB<<<469, 256, 0, stream>>>(Pws, PA, alpha, aiF);
    gcn_kC<<<1024, 256, 0, stream>>>(x, aiF, Wd, bd, gamma, beta, out, meanT);
    gcn_kD<<<64, 256, 0, stream>>>(meanT, Wsa, bsa, g2p);
    gcn_kE<<<4096, 256, 0, stream>>>(out, g2p, M2);
    gcn_kFG<<<64, 256, 0, stream>>>(M2, Wta, bta, W1, b1, W2, b2, g3p, g4p);
    gcn_kH<<<4096, 256, 0, stream>>>(out, g2p, g3p, g4p);
}

// Round 9
// 622.488 us; speedup vs baseline: 1.0784x; 1.0784x over previous
//
#include <hip/hip_runtime.h>
#include <math.h>

// Problem constants
// N=64, C=64 (=Cout), T=256, V=25, S=3, inter=16
// x: [N,C,T,V] fp32;  out: [N,C,T,V] fp32

typedef __attribute__((ext_vector_type(8))) __bf16 bf16x8;
typedef __attribute__((ext_vector_type(4))) float  f32x4;

#define AIF_HALF 196608   // bf16 elements in hi (and in lo) fragment tensor

// ---------------------------------------------------------------------------
// Kernel A (unchanged from R7): grid = 1024 blocks (n*16 + tt), 4 waves.
// ---------------------------------------------------------------------------
__global__ __launch_bounds__(256, 3) void gcn_kA(const float* __restrict__ x,
                                                 const float* __restrict__ Wa,
                                                 const float* __restrict__ ba,
                                                 const float* __restrict__ Wb,
                                                 const float* __restrict__ bb,
                                                 float* __restrict__ Pws) {
    const int bid = blockIdx.x;      // n*16 + tt
    const int n  = bid >> 4;
    const int tt = bid & 15;
    const int tid  = threadIdx.x;
    const int lane = tid & 63;
    const int wv   = tid >> 6;
    const int col  = lane & 15;
    const int quad = lane >> 4;

    __shared__ __align__(16) __bf16 xB[112 * 72];      // [q][c]  16,128 B
    __shared__ __align__(16) __bf16 aT[3][32 * 72];    // [s][v][k] 13,824 B
    __shared__ __align__(16) __bf16 bT[3][32 * 72];    // [s][v][k] 13,824 B

    for (int j = tid; j < 12 * 72; j += 256) xB[100 * 72 + j] = (__bf16)0.f;
    for (int j = tid; j < 7 * 72; j += 256) {
        #pragma unroll
        for (int s = 0; s < 3; ++s) {
            aT[s][25 * 72 + j] = (__bf16)0.f;
            bT[s][25 * 72 + j] = (__bf16)0.f;
        }
    }

    bf16x8 waf0[3], waf1[3], wbf0[3], wbf1[3];
    float ba4[3][4], bb4[3][4];
    #pragma unroll
    for (int s = 0; s < 3; ++s) {
        const float* wap = Wa + (size_t)s * 1024 + col * 64 + quad * 8;
        const float* wbp = Wb + (size_t)s * 1024 + col * 64 + quad * 8;
        #pragma unroll
        for (int j = 0; j < 8; ++j) { waf0[s][j] = (__bf16)wap[j];      wbf0[s][j] = (__bf16)wbp[j]; }
        #pragma unroll
        for (int j = 0; j < 8; ++j) { waf1[s][j] = (__bf16)wap[32 + j]; wbf1[s][j] = (__bf16)wbp[32 + j]; }
        #pragma unroll
        for (int r = 0; r < 4; ++r) {
            ba4[s][r] = ba[s * 16 + quad * 4 + r];
            bb4[s][r] = bb[s * 16 + quad * 4 + r];
        }
    }

    f32x4 pacc[3];
    #pragma unroll
    for (int s = 0; s < 3; ++s) pacc[s] = (f32x4){0.f, 0.f, 0.f, 0.f};
    const int mi = wv >> 1, ni = wv & 1;

    const float* xbase = x + (size_t)n * 409600 + tt * 400;

    for (int cc = 0; cc < 4; ++cc) {
        __syncthreads();
        const float* xc = xbase + cc * 100;
        #pragma unroll
        for (int it = 0; it < 7; ++it) {
            int j4 = tid + it * 256;
            if (j4 < 1600) {
                int c  = j4 / 25;
                int qq = (j4 - c * 25) * 4;
                float4 xv = *(const float4*)(xc + c * 6400 + qq);
                __bf16* dst = &xB[qq * 72 + c];
                dst[0]   = (__bf16)xv.x;
                dst[72]  = (__bf16)xv.y;
                dst[144] = (__bf16)xv.z;
                dst[216] = (__bf16)xv.w;
            }
        }
        __syncthreads();

        #pragma unroll
        for (int s = 0; s < 3; ++s) {
            for (int jt = wv; jt < 7; jt += 4) {
                int q = jt * 16 + col;
                const __bf16* bp = &xB[q * 72 + quad * 8];
                bf16x8 b0 = *(const bf16x8*)bp;
                bf16x8 b1 = *(const bf16x8*)(bp + 32);
                f32x4 da = {0.f, 0.f, 0.f, 0.f}, db = {0.f, 0.f, 0.f, 0.f};
                da = __builtin_amdgcn_mfma_f32_16x16x32_bf16(waf0[s], b0, da, 0, 0, 0);
                da = __builtin_amdgcn_mfma_f32_16x16x32_bf16(waf1[s], b1, da, 0, 0, 0);
                db = __builtin_amdgcn_mfma_f32_16x16x32_bf16(wbf0[s], b0, db, 0, 0, 0);
                db = __builtin_amdgcn_mfma_f32_16x16x32_bf16(wbf1[s], b1, db, 0, 0, 0);
                if (q < 100) {
                    int tl = q / 25, v = q - tl * 25;
                    #pragma unroll
                    for (int r = 0; r < 4; ++r) {
                        int k = (quad * 4 + r) * 4 + tl;   // i*4 + tl
                        aT[s][v * 72 + k] = (__bf16)(da[r] + ba4[s][r]);
                        bT[s][v * 72 + k] = (__bf16)(db[r] + bb4[s][r]);
                    }
                }
            }
        }
        __syncthreads();

        #pragma unroll
        for (int s = 0; s < 3; ++s) {
            #pragma unroll
            for (int k0 = 0; k0 < 64; k0 += 32) {
                bf16x8 af  = *(const bf16x8*)&aT[s][(mi * 16 + col) * 72 + k0 + quad * 8];
                bf16x8 bfr = *(const bf16x8*)&bT[s][(ni * 16 + col) * 72 + k0 + quad * 8];
                pacc[s] = __builtin_amdgcn_mfma_f32_16x16x32_bf16(af, bfr, pacc[s], 0, 0, 0);
            }
        }
    }

    #pragma unroll
    for (int s = 0; s < 3; ++s) {
        #pragma unroll
        for (int r = 0; r < 4; ++r) {
            int v = mi * 16 + quad * 4 + r;
            int w = ni * 16 + col;
            if (v < 25 && w < 25)
                atomicAdd(&Pws[(size_t)(s * 64 + n) * 625 + v * 25 + w], pacc[s][r]);
        }
    }
}

// ---------------------------------------------------------------------------
// Kernel B (unchanged from R9): Ai in MFMA B-fragment layout, bf16 hi+lo.
// ---------------------------------------------------------------------------
__global__ __launch_bounds__(256) void gcn_kB(const float* __restrict__ Pws,
                                              const float* __restrict__ PA,
                                              const float* __restrict__ alpha,
                                              __bf16* __restrict__ aiF) {
    int j = blockIdx.x * 256 + threadIdx.x;
    if (j < 120000) {
        int sn = j / 625;
        int r  = j - sn * 625;
        int s  = sn >> 6;
        float val = PA[s * 625 + r] + alpha[0] * tanhf(Pws[j] * (1.f / 4096.f));
        int k  = r / 25;
        int nn = r - k * 25;
        int vt = nn >> 4, colx = nn & 15;
        int idx = ((sn * 2 + vt) << 9) + (colx << 5) + k;
        __bf16 h = (__bf16)val;
        aiF[idx]            = h;
        aiF[AIF_HALF + idx] = (__bf16)(val - (float)h);
    }
}

// ---------------------------------------------------------------------------
// Kernel C (R11 = R9 structure + spill-free coalesced epilogue):
//   per (n, tt) block, 4 chunks of 4 t:
//     stage xB[q][c] (block-wide, float4);
//     for s: u_s = Wd[s]@x (MFMA) -> uLw (wave-private); acc += uLw x Ai_s
//     phase 1 (regs+LDS only): resid from xB (bf16), val=relu(BN+resid),
//              msum[4][2] += val (static regs), val -> ySw (aliases uLw)
//     phase 2: pure LDS->global: f32x4 ySw -> float4 y1 (contiguous 400B/row)
//   No global residual re-read; no long-lived register arrays (no spill).
//   2 barriers/chunk. LDS = 16,128 + 26,624 = 42,752 B -> 3 blocks/CU.
// ---------------------------------------------------------------------------
__global__ __launch_bounds__(256, 3) void gcn_kC(const float* __restrict__ x,
                                              const __bf16* __restrict__ aiF,
                                              const float* __restrict__ Wd,
                                              const float* __restrict__ bd,
                                              const float* __restrict__ gamma,
                                              const float* __restrict__ beta,
                                              float* __restrict__ y1,
                                              float* __restrict__ meanT) {
    const int bid = blockIdx.x;
    const int tt = bid & 15;
    const int n  = bid >> 4;
    const int tid  = threadIdx.x;
    const int lane = tid & 63;
    const int wv   = tid >> 6;
    const int col  = lane & 15;
    const int quad = lane >> 4;

    __shared__ __align__(16) __bf16 xB[112 * 72];           // 16,128 B
    // per-wave union region (6,656 B each):
    //   uL view: 64 rows x 40 bf16 (80 B row stride, first 5,120 B)
    //   yS view: 16 rows x 104 f32 (416 B row stride, all 6,656 B)
    __shared__ __align__(16) unsigned char uY[4 * 6656];    // 26,624 B

    __bf16* uLw = (__bf16*)(uY + wv * 6656);
    float*  ySw = (float*) (uY + wv * 6656);

    // init: xB pad rows; uLw pad cols 25..31 (read by agg MFMA quad-3 frag)
    for (int j = tid; j < 12 * 72; j += 256) xB[100 * 72 + j] = (__bf16)0.f;
    {
        __bf16* rz = uLw + lane * 40;
        #pragma unroll
        for (int k = 25; k < 32; ++k) rz[k] = (__bf16)0.f;
    }

    // Ai B-fragments: coalesced b128 loads from fragment tensor (12 loads)
    bf16x8 aiH[3][2], aiL[3][2];
    #pragma unroll
    for (int s = 0; s < 3; ++s) {
        #pragma unroll
        for (int vt = 0; vt < 2; ++vt) {
            const __bf16* p = aiF + ((size_t)((s * 64 + n) * 2 + vt)) * 512
                                  + col * 32 + quad * 8;
            aiH[s][vt] = *(const bf16x8*)p;
            aiL[s][vt] = *(const bf16x8*)(p + AIF_HALF);
        }
    }

    // Wd A-fragments: A[m=o=wv*16+col][k=c]
    bf16x8 wd0[3], wd1[3];
    #pragma unroll
    for (int s = 0; s < 3; ++s) {
        const float* wdp = Wd + (size_t)(s * 64 + wv * 16 + col) * 64 + quad * 8;
        #pragma unroll
        for (int j = 0; j < 8; ++j) wd0[s][j] = (__bf16)wdp[j];
        #pragma unroll
        for (int j = 0; j < 8; ++j) wd1[s][j] = (__bf16)wdp[32 + j];
    }

    // epilogue constants, per ml (o = wv*16 + ml*4 + quad)
    float scv[4], btv[4], bdsv[4];
    #pragma unroll
    for (int ml = 0; ml < 4; ++ml) {
        int o = wv * 16 + ml * 4 + quad;
        scv[ml]  = gamma[o] * rsqrtf(1.f + 1e-5f);
        btv[ml]  = beta[o];
        bdsv[ml] = bd[o] + bd[64 + o] + bd[128 + o];
    }

    float msum[4][2];
    #pragma unroll
    for (int ml = 0; ml < 4; ++ml) { msum[ml][0] = 0.f; msum[ml][1] = 0.f; }

    const float* xbase = x + (size_t)n * 409600 + tt * 400;
    float*       ygw   = y1 + (size_t)(n * 64 + wv * 16) * 6400 + tt * 400;

    for (int cc = 0; cc < 4; ++cc) {
        f32x4 acc[4][2];
        #pragma unroll
        for (int ml = 0; ml < 4; ++ml) {
            acc[ml][0] = (f32x4){0.f, 0.f, 0.f, 0.f};
            acc[ml][1] = (f32x4){0.f, 0.f, 0.f, 0.f};
        }

        __syncthreads();   // all waves done with xB (MFMA reads + residual reads)
        // stage xB[q][c]: block-wide float4 over q (R9 pattern)
        const float* xc = xbase + cc * 100;
        #pragma unroll
        for (int it = 0; it < 7; ++it) {
            int j4 = tid + it * 256;
            if (j4 < 1600) {
                int c  = j4 / 25;
                int qq = (j4 - c * 25) * 4;
                float4 xv = *(const float4*)(xc + c * 6400 + qq);
                __bf16* dst = &xB[qq * 72 + c];
                dst[0]   = (__bf16)xv.x;
                dst[72]  = (__bf16)xv.y;
                dst[144] = (__bf16)xv.z;
                dst[216] = (__bf16)xv.w;
            }
        }
        __syncthreads();

        #pragma unroll
        for (int s = 0; s < 3; ++s) {
            // u MFMA: wave wv owns o-tile wv; 7 q-tiles of 16 (uLw wave-private)
            #pragma unroll
            for (int qt = 0; qt < 7; ++qt) {
                const __bf16* bp = &xB[(qt * 16 + col) * 72 + quad * 8];
                bf16x8 b0 = *(const bf16x8*)bp;
                bf16x8 b1 = *(const bf16x8*)(bp + 32);
                f32x4 u = {0.f, 0.f, 0.f, 0.f};
                u = __builtin_amdgcn_mfma_f32_16x16x32_bf16(wd0[s], b0, u, 0, 0, 0);
                u = __builtin_amdgcn_mfma_f32_16x16x32_bf16(wd1[s], b1, u, 0, 0, 0);
                int q = qt * 16 + col;       // D col
                if (q < 100) {
                    int trel = q / 25, v = q - trel * 25;
                    int rowbase = (quad * 16 + trel) * 40 + v;   // row (quad*4+r)*4+trel
                    uLw[rowbase]       = (__bf16)u[0];
                    uLw[rowbase + 160] = (__bf16)u[1];
                    uLw[rowbase + 320] = (__bf16)u[2];
                    uLw[rowbase + 480] = (__bf16)u[3];
                }
            }
            // aggregation MFMA: same wave's uLw rows; no barrier
            #pragma unroll
            for (int ml = 0; ml < 4; ++ml) {
                bf16x8 af = *(const bf16x8*)&uLw[(ml * 16 + col) * 40 + quad * 8];
                acc[ml][0] = __builtin_amdgcn_mfma_f32_16x16x32_bf16(af, aiH[s][0], acc[ml][0], 0, 0, 0);
                acc[ml][1] = __builtin_amdgcn_mfma_f32_16x16x32_bf16(af, aiH[s][1], acc[ml][1], 0, 0, 0);
                acc[ml][0] = __builtin_amdgcn_mfma_f32_16x16x32_bf16(af, aiL[s][0], acc[ml][0], 0, 0, 0);
                acc[ml][1] = __builtin_amdgcn_mfma_f32_16x16x32_bf16(af, aiL[s][1], acc[ml][1], 0, 0, 0);
            }
        }

        // phase 1: full epilogue value in regs (resid from xB bf16), msum
        // accumulate (static), store to ySw (wave-private; aliases dead uLw)
        #pragma unroll
        for (int ml = 0; ml < 4; ++ml) {
            int ol = ml * 4 + quad;
            int o  = wv * 16 + ol;
            #pragma unroll
            for (int vt = 0; vt < 2; ++vt) {
                int v = vt * 16 + col;
                if (v < 25) {
                    float ms = 0.f;
                    #pragma unroll
                    for (int r = 0; r < 4; ++r) {
                        float resid = (float)xB[(r * 25 + v) * 72 + o];
                        float val = scv[ml] * (acc[ml][vt][r] + bdsv[ml]) + btv[ml]
                                  + resid;
                        val = val > 0.f ? val : 0.f;
                        ySw[ol * 104 + r * 25 + v] = val;
                        ms += val;
                    }
                    msum[ml][vt] += ms;
                }
            }
        }

        // phase 2 (same wave): pure LDS->global, float4 coalesced
        float* yc2 = ygw + cc * 100;
        #pragma unroll
        for (int it = 0; it < 7; ++it) {
            int j = lane + it * 64;
            if (j < 400) {
                int cl = j / 25;
                int qq = (j - cl * 25) * 4;
                f32x4 yv = *(const f32x4*)&ySw[cl * 104 + qq];
                float4 o4;
                o4.x = yv[0]; o4.y = yv[1]; o4.z = yv[2]; o4.w = yv[3];
                *(float4*)(yc2 + cl * 6400 + qq) = o4;
            }
        }

        // re-zero uLw pad cols (clobbered by ySw; needed by next chunk's agg)
        {
            __bf16* rz = uLw + lane * 40;
            #pragma unroll
            for (int k = 25; k < 32; ++k) rz[k] = (__bf16)0.f;
        }
    }

    // meanT partial sums (over this block's 16 t) — R9 scheme, 8 atomics/thread
    #pragma unroll
    for (int ml = 0; ml < 4; ++ml) {
        int o = wv * 16 + ml * 4 + quad;
        #pragma unroll
        for (int vt = 0; vt < 2; ++vt) {
            int v = vt * 16 + col;
            if (v < 25)
                atomicAdd(&meanT[(n * 64 + o) * 25 + v], msum[ml][vt]);
        }
    }
}

// ---------------------------------------------------------------------------
// Kernel D: spatial SE gate.  g2p[n][v] = 1 + sigmoid(conv_V(meanT/T, Wsa)+bsa)
// ---------------------------------------------------------------------------
__global__ __launch_bounds__(256) void gcn_kD(const float* __restrict__ meanT,
                                              const float* __restrict__ Wsa,
                                              const float* __restrict__ bsa,
                                              float* __restrict__ g2p) {
    const int n = blockIdx.x;
    const int tid = threadIdx.x;
    __shared__ float sm[1600], wl[1600];
    for (int j = tid; j < 1600; j += 256) {
        sm[j] = meanT[n * 1600 + j] * (1.f / 256.f);
        wl[j] = Wsa[j];
    }
    __syncthreads();
    if (tid < 25) {
        float acc = bsa[0];
        for (int c = 0; c < 64; ++c) {
            #pragma unroll
            for (int k = 0; k < 25; ++k) {
                int j = tid + k - 12;
                if (j >= 0 && j < 25) acc += sm[c * 25 + j] * wl[c * 25 + k];
            }
        }
        g2p[n * 25 + tid] = 1.f + 1.f / (1.f + expf(-acc));
    }
}

// ---------------------------------------------------------------------------
// Kernel E: M2[n][c][t] = (1/V) sum_v y1 * g2p[n][v]  (float4 staging)
// ---------------------------------------------------------------------------
__global__ __launch_bounds__(256) void gcn_kE(const float* __restrict__ y1,
                                              const float* __restrict__ g2p,
                                              float* __restrict__ M2) {
    const int bid = blockIdx.x;     // n*64 + c
    const int n = bid >> 6;
    const int tid = threadIdx.x;
    __shared__ float yl[6400];
    __shared__ float g2l[25];
    const float4* yp = (const float4*)(y1 + (size_t)bid * 6400);
    float4* ylv = (float4*)yl;
    for (int j = tid; j < 1600; j += 256) ylv[j] = yp[j];
    if (tid < 25) g2l[tid] = g2p[n * 25 + tid];
    __syncthreads();
    float sum = 0.f;
    #pragma unroll
    for (int v = 0; v < 25; ++v) sum += yl[tid * 25 + v] * g2l[v];
    M2[bid * 256 + tid] = sum * 0.04f;
}

// ---------------------------------------------------------------------------
// Kernel FG (merge of kF+kG): per n, stage M2[n] in LDS once, then
//   g3[t] = 1 + sigmoid(conv_T(M2, Wta)+bta)
//   M3[c] = (1/T) sum_t M2[c][t]*g3[t];  MLP -> g4[c] = 1+sigmoid
// ---------------------------------------------------------------------------
__global__ __launch_bounds__(256) void gcn_kFG(const float* __restrict__ M2,
                                               const float* __restrict__ Wta,
                                               const float* __restrict__ bta,
                                               const float* __restrict__ W1,
                                               const float* __restrict__ b1,
                                               const float* __restrict__ W2,
                                               const float* __restrict__ b2,
                                               float* __restrict__ g3p,
                                               float* __restrict__ g4p) {
    const int n = blockIdx.x;
    const int tid = threadIdx.x;
    __shared__ float m2L[64 * 260];   // [c][t], pad 260
    __shared__ float wl[576];
    __shared__ float g3l[256], part[256], M3[64], h[32];

    for (int j = tid; j < 16384; j += 256) {
        int c = j >> 8, t = j & 255;
        m2L[c * 260 + t] = M2[(size_t)n * 16384 + j];
    }
    for (int j = tid; j < 576; j += 256) wl[j] = Wta[j];
    __syncthreads();

    // phase F: temporal conv (kernel 9, pad 4), t = tid
    {
        const int t = tid;
        float acc = bta[0];
        for (int c = 0; c < 64; ++c) {
            const float* mp = &m2L[c * 260];
            #pragma unroll
            for (int k = 0; k < 9; ++k) {
                int j = t + k - 4;
                if (j >= 0 && j < 256) acc += mp[j] * wl[c * 9 + k];
            }
        }
        float g3 = 1.f + 1.f / (1.f + expf(-acc));
        g3l[t] = g3;
        g3p[n * 256 + t] = g3;
    }
    __syncthreads();

    // phase G: channel SE
    {
        const int c = tid >> 2, q = tid & 3;
        float p = 0.f;
        const float* mp = &m2L[c * 260 + q * 64];
        #pragma unroll 16
        for (int j = 0; j < 64; ++j) p += mp[j] * g3l[q * 64 + j];
        part[tid] = p;
    }
    __syncthreads();
    if (tid < 64)
        M3[tid] = (part[tid * 4] + part[tid * 4 + 1] + part[tid * 4 + 2] +
                   part[tid * 4 + 3]) * (1.f / 256.f);
    __syncthreads();
    if (tid < 32) {
        float acc = b1[tid];
        #pragma unroll 16
        for (int cc = 0; cc < 64; ++cc) acc += W1[tid * 64 + cc] * M3[cc];
        h[tid] = acc > 0.f ? acc : 0.f;
    }
    __syncthreads();
    if (tid < 64) {
        float acc = b2[tid];
        #pragma unroll
        for (int j = 0; j < 32; ++j) acc += W2[tid * 32 + j] * h[j];
        g4p[n * 64 + tid] = 1.f + 1.f / (1.f + expf(-acc));
    }
}

// ---------------------------------------------------------------------------
// Kernel H: final gating, in place:  y = y1 * g2p[v] * g3p[t] * g4p[c]
// ---------------------------------------------------------------------------
__global__ __launch_bounds__(256) void gcn_kH(float* __restrict__ y,
                                              const float* __restrict__ g2p,
                                              const float* __restrict__ g3p,
                                              const float* __restrict__ g4p) {
    const int bid = blockIdx.x;  // n*64 + c
    const int n = bid >> 6;
    const int tid = threadIdx.x;
    __shared__ float g3l[256], g2l[25];
    g3l[tid] = g3p[n * 256 + tid];
    if (tid < 25) g2l[tid] = g2p[n * 25 + tid];
    const float g4 = g4p[bid];
    __syncthreads();
    float4* yp = (float4*)(y + (size_t)bid * 6400);
    for (int f = tid; f < 1600; f += 256) {
        float4 val = yp[f];
        float* vv = (float*)&val;
        const int base = f * 4;
        #pragma unroll
        for (int k = 0; k < 4; ++k) {
            int idx = base + k;
            int t = (int)(((unsigned long long)idx * 1374389535ull) >> 35);
            int v = idx - t * 25;
            vv[k] *= g2l[v] * g3l[t] * g4;
        }
        yp[f] = val;
    }
}

// ---------------------------------------------------------------------------
extern "C" void kernel_launch(void* const* d_in, const int* in_sizes, int n_in,
                              void* d_out, int out_size, void* d_ws, size_t ws_size,
                              hipStream_t stream) {
    const float* x     = (const float*)d_in[0];
    const float* PA    = (const float*)d_in[1];
    const float* alpha = (const float*)d_in[2];
    const float* Wa    = (const float*)d_in[3];
    const float* ba    = (const float*)d_in[4];
    const float* Wb    = (const float*)d_in[5];
    const float* bb    = (const float*)d_in[6];
    const float* Wd    = (const float*)d_in[7];
    const float* bd    = (const float*)d_in[8];
    const float* gamma = (const float*)d_in[9];
    const float* beta  = (const float*)d_in[10];
    const float* Wsa   = (const float*)d_in[11];
    const float* bsa   = (const float*)d_in[12];
    const float* Wta   = (const float*)d_in[13];
    const float* bta   = (const float*)d_in[14];
    const float* W1    = (const float*)d_in[15];
    const float* b1    = (const float*)d_in[16];
    const float* W2    = (const float*)d_in[17];
    const float* b2    = (const float*)d_in[18];

    float* out = (float*)d_out;
    float* ws  = (float*)d_ws;

    // workspace layout (floats)
    float*  Pws   = ws;                        // 120000  (zeroed; kA atomics)
    float*  meanT = ws + 120000;               // 102400  (zeroed; kC atomics)
    __bf16* aiF   = (__bf16*)(ws + 222400);    // 393216 bf16 = 196608 f (zeroed pads)
    float*  M2    = ws + 419008;               // 4194304
    float*  g2p   = ws + 4613312;              // 1600
    float*  g3p   = ws + 4614912;              // 16384
    float*  g4p   = ws + 4631296;              // 4096

    hipMemsetAsync(ws, 0, 222400 * sizeof(float), stream);   // Pws + meanT
    hipMemsetAsync(aiF, 0, 786432, stream);                  // aiF (incl. pads)

    gcn_kA<<<1024, 256, 0, stream>>>(x, Wa, ba, Wb, bb, Pws);
    gcn_kB<<<469, 256, 0, stream>>>(Pws, PA, alpha, aiF);
    gcn_kC<<<1024, 256, 0, stream>>>(x, aiF, Wd, bd, gamma, beta, out, meanT);
    gcn_kD<<<64, 256, 0, stream>>>(meanT, Wsa, bsa, g2p);
    gcn_kE<<<4096, 256, 0, stream>>>(out, g2p, M2);
    gcn_kFG<<<64, 256, 0, stream>>>(M2, Wta, bta, W1, b1, W2, b2, g3p, g4p);
    gcn_kH<<<4096, 256, 0, stream>>>(out, g2p, g3p, g4p);
}

// Round 10
// 591.044 us; speedup vs baseline: 1.1358x; 1.0532x over previous
//
#include <hip/hip_runtime.h>
#include <math.h>

// Problem constants
// N=64, C=64 (=Cout), T=256, V=25, S=3, inter=16
// x: [N,C,T,V] fp32;  out: [N,C,T,V] fp32

typedef __attribute__((ext_vector_type(8))) __bf16 bf16x8;
typedef __attribute__((ext_vector_type(4))) float  f32x4;

#define AIF_HALF 196608   // bf16 elements in hi (and in lo) fragment tensor

// ---------------------------------------------------------------------------
// Kernel A (R12: 2-barrier pipelined schedule — stage(cc+1) overlaps Gram(cc);
// embed work rotation 6/5/5/5). grid = 1024 blocks (n*16 + tt), 4 waves.
//   per chunk: [bar] embed(cc) [bar] { stage(cc+1) || Gram(cc) }
// Partial P atomicAdd'ed to Pws; kB applies tanh epilogue.
// LDS = 16,128 + 2*3*4,608 = 43,776 B -> 3 blocks/CU.
// ---------------------------------------------------------------------------
__global__ __launch_bounds__(256, 3) void gcn_kA(const float* __restrict__ x,
                                                 const float* __restrict__ Wa,
                                                 const float* __restrict__ ba,
                                                 const float* __restrict__ Wb,
                                                 const float* __restrict__ bb,
                                                 float* __restrict__ Pws) {
    const int bid = blockIdx.x;      // n*16 + tt
    const int n  = bid >> 4;
    const int tt = bid & 15;
    const int tid  = threadIdx.x;
    const int lane = tid & 63;
    const int wv   = tid >> 6;
    const int col  = lane & 15;
    const int quad = lane >> 4;

    __shared__ __align__(16) __bf16 xB[112 * 72];      // [q][c]  16,128 B
    __shared__ __align__(16) __bf16 aT[3][32 * 72];    // [s][v][k] 13,824 B
    __shared__ __align__(16) __bf16 bT[3][32 * 72];    // [s][v][k] 13,824 B

    for (int j = tid; j < 12 * 72; j += 256) xB[100 * 72 + j] = (__bf16)0.f;
    for (int j = tid; j < 7 * 72; j += 256) {
        #pragma unroll
        for (int s = 0; s < 3; ++s) {
            aT[s][25 * 72 + j] = (__bf16)0.f;
            bT[s][25 * 72 + j] = (__bf16)0.f;
        }
    }

    bf16x8 waf0[3], waf1[3], wbf0[3], wbf1[3];
    float ba4[3][4], bb4[3][4];
    #pragma unroll
    for (int s = 0; s < 3; ++s) {
        const float* wap = Wa + (size_t)s * 1024 + col * 64 + quad * 8;
        const float* wbp = Wb + (size_t)s * 1024 + col * 64 + quad * 8;
        #pragma unroll
        for (int j = 0; j < 8; ++j) { waf0[s][j] = (__bf16)wap[j];      wbf0[s][j] = (__bf16)wbp[j]; }
        #pragma unroll
        for (int j = 0; j < 8; ++j) { waf1[s][j] = (__bf16)wap[32 + j]; wbf1[s][j] = (__bf16)wbp[32 + j]; }
        #pragma unroll
        for (int r = 0; r < 4; ++r) {
            ba4[s][r] = ba[s * 16 + quad * 4 + r];
            bb4[s][r] = bb[s * 16 + quad * 4 + r];
        }
    }

    f32x4 pacc[3];
    #pragma unroll
    for (int s = 0; s < 3; ++s) pacc[s] = (f32x4){0.f, 0.f, 0.f, 0.f};
    const int mi = wv >> 1, ni = wv & 1;

    const float* xbase = x + (size_t)n * 409600 + tt * 400;

    // stage chunk 0
    {
        const float* xc = xbase;
        #pragma unroll
        for (int it = 0; it < 7; ++it) {
            int j4 = tid + it * 256;
            if (j4 < 1600) {
                int c  = j4 / 25;
                int qq = (j4 - c * 25) * 4;
                float4 xv = *(const float4*)(xc + c * 6400 + qq);
                __bf16* dst = &xB[qq * 72 + c];
                dst[0]   = (__bf16)xv.x;
                dst[72]  = (__bf16)xv.y;
                dst[144] = (__bf16)xv.z;
                dst[216] = (__bf16)xv.w;
            }
        }
    }

    for (int cc = 0; cc < 4; ++cc) {
        __syncthreads();   // xB(cc) visible; aT/bT free (prev Gram done)

        // embed: s static; jt rotation balances 6/5/5/5 across waves
        #pragma unroll
        for (int s = 0; s < 3; ++s) {
            int rw = (wv + s) & 3;
            #pragma unroll
            for (int rep = 0; rep < 2; ++rep) {
                int jt = rw + rep * 4;
                if (jt < 7) {
                    int q = jt * 16 + col;
                    const __bf16* bp = &xB[q * 72 + quad * 8];
                    bf16x8 b0 = *(const bf16x8*)bp;
                    bf16x8 b1 = *(const bf16x8*)(bp + 32);
                    f32x4 da = {0.f, 0.f, 0.f, 0.f}, db = {0.f, 0.f, 0.f, 0.f};
                    da = __builtin_amdgcn_mfma_f32_16x16x32_bf16(waf0[s], b0, da, 0, 0, 0);
                    da = __builtin_amdgcn_mfma_f32_16x16x32_bf16(waf1[s], b1, da, 0, 0, 0);
                    db = __builtin_amdgcn_mfma_f32_16x16x32_bf16(wbf0[s], b0, db, 0, 0, 0);
                    db = __builtin_amdgcn_mfma_f32_16x16x32_bf16(wbf1[s], b1, db, 0, 0, 0);
                    if (q < 100) {
                        int tl = q / 25, v = q - tl * 25;
                        #pragma unroll
                        for (int r = 0; r < 4; ++r) {
                            int k = (quad * 4 + r) * 4 + tl;   // i*4 + tl
                            aT[s][v * 72 + k] = (__bf16)(da[r] + ba4[s][r]);
                            bT[s][v * 72 + k] = (__bf16)(db[r] + bb4[s][r]);
                        }
                    }
                }
            }
        }
        __syncthreads();   // aT/bT visible; xB free to overwrite

        // stage(cc+1): global loads issue here, latency hides under Gram
        if (cc < 3) {
            const float* xc = xbase + (cc + 1) * 100;
            #pragma unroll
            for (int it = 0; it < 7; ++it) {
                int j4 = tid + it * 256;
                if (j4 < 1600) {
                    int c  = j4 / 25;
                    int qq = (j4 - c * 25) * 4;
                    float4 xv = *(const float4*)(xc + c * 6400 + qq);
                    __bf16* dst = &xB[qq * 72 + c];
                    dst[0]   = (__bf16)xv.x;
                    dst[72]  = (__bf16)xv.y;
                    dst[144] = (__bf16)xv.z;
                    dst[216] = (__bf16)xv.w;
                }
            }
        }

        // Gram: wave wv owns (mi,ni) quadrant; K=64 per chunk
        #pragma unroll
        for (int s = 0; s < 3; ++s) {
            #pragma unroll
            for (int k0 = 0; k0 < 64; k0 += 32) {
                bf16x8 af  = *(const bf16x8*)&aT[s][(mi * 16 + col) * 72 + k0 + quad * 8];
                bf16x8 bfr = *(const bf16x8*)&bT[s][(ni * 16 + col) * 72 + k0 + quad * 8];
                pacc[s] = __builtin_amdgcn_mfma_f32_16x16x32_bf16(af, bfr, pacc[s], 0, 0, 0);
            }
        }
    }

    #pragma unroll
    for (int s = 0; s < 3; ++s) {
        #pragma unroll
        for (int r = 0; r < 4; ++r) {
            int v = mi * 16 + quad * 4 + r;
            int w = ni * 16 + col;
            if (v < 25 && w < 25)
                atomicAdd(&Pws[(size_t)(s * 64 + n) * 625 + v * 25 + w], pacc[s][r]);
        }
    }
}

// ---------------------------------------------------------------------------
// Kernel B (unchanged): Ai in MFMA B-fragment layout, bf16 hi+lo.
// ---------------------------------------------------------------------------
__global__ __launch_bounds__(256) void gcn_kB(const float* __restrict__ Pws,
                                              const float* __restrict__ PA,
                                              const float* __restrict__ alpha,
                                              __bf16* __restrict__ aiF) {
    int j = blockIdx.x * 256 + threadIdx.x;
    if (j < 120000) {
        int sn = j / 625;
        int r  = j - sn * 625;
        int s  = sn >> 6;
        float val = PA[s * 625 + r] + alpha[0] * tanhf(Pws[j] * (1.f / 4096.f));
        int k  = r / 25;
        int nn = r - k * 25;
        int vt = nn >> 4, colx = nn & 15;
        int idx = ((sn * 2 + vt) << 9) + (colx << 5) + k;
        __bf16 h = (__bf16)val;
        aiF[idx]            = h;
        aiF[AIF_HALF + idx] = (__bf16)(val - (float)h);
    }
}

// ---------------------------------------------------------------------------
// Kernel C (R12 = exact R9 revert: known 209 µs config):
//   per (n, tt) block, 4 chunks of 4 t:
//     stage xB[q][c] once; for s: u_s = Wd[s]@x (MFMA) -> uL (wave-private rows);
//     acc += uL x Ai_s (MFMA over K=w, Ai split bf16 hi+lo).  2 barriers/chunk.
// ---------------------------------------------------------------------------
__global__ __launch_bounds__(256, 3) void gcn_kC(const float* __restrict__ x,
                                              const __bf16* __restrict__ aiF,
                                              const float* __restrict__ Wd,
                                              const float* __restrict__ bd,
                                              const float* __restrict__ gamma,
                                              const float* __restrict__ beta,
                                              float* __restrict__ y1,
                                              float* __restrict__ meanT) {
    const int bid = blockIdx.x;
    const int tt = bid & 15;
    const int n  = bid >> 4;
    const int tid  = threadIdx.x;
    const int lane = tid & 63;
    const int wv   = tid >> 6;
    const int col  = lane & 15;
    const int quad = lane >> 4;

    __shared__ __align__(16) __bf16 xB[112 * 72];   // [q][c]  16,128 B
    __shared__ __align__(16) __bf16 uL[256 * 40];   // [(o*4+trel)][w] 20,480 B

    // one-time zero of pad regions
    for (int j = tid; j < 12 * 72; j += 256) xB[100 * 72 + j] = (__bf16)0.f;
    for (int j = tid; j < 256 * 15; j += 256) {
        int r = j / 15;
        int e = j - r * 15;
        uL[r * 40 + 25 + e] = (__bf16)0.f;   // cols 25..39 stay zero forever
    }

    // Ai B-fragments: coalesced b128 loads from fragment tensor (12 loads)
    bf16x8 aiH[3][2], aiL[3][2];
    #pragma unroll
    for (int s = 0; s < 3; ++s) {
        #pragma unroll
        for (int vt = 0; vt < 2; ++vt) {
            const __bf16* p = aiF + ((size_t)((s * 64 + n) * 2 + vt)) * 512
                                  + col * 32 + quad * 8;
            aiH[s][vt] = *(const bf16x8*)p;
            aiL[s][vt] = *(const bf16x8*)(p + AIF_HALF);
        }
    }

    // Wd A-fragments: A[m=o=wv*16+col][k=c]
    bf16x8 wd0[3], wd1[3];
    #pragma unroll
    for (int s = 0; s < 3; ++s) {
        const float* wdp = Wd + (size_t)(s * 64 + wv * 16 + col) * 64 + quad * 8;
        #pragma unroll
        for (int j = 0; j < 8; ++j) wd0[s][j] = (__bf16)wdp[j];
        #pragma unroll
        for (int j = 0; j < 8; ++j) wd1[s][j] = (__bf16)wdp[32 + j];
    }

    // epilogue constants, per ml (o = (wv*4+ml)*4 + quad)
    float scv[4], btv[4], bdsv[4];
    #pragma unroll
    for (int ml = 0; ml < 4; ++ml) {
        int o = (wv * 4 + ml) * 4 + quad;
        scv[ml]  = gamma[o] * rsqrtf(1.f + 1e-5f);
        btv[ml]  = beta[o];
        bdsv[ml] = bd[o] + bd[64 + o] + bd[128 + o];
    }

    float msum[4][2];
    #pragma unroll
    for (int ml = 0; ml < 4; ++ml) { msum[ml][0] = 0.f; msum[ml][1] = 0.f; }

    const float* xbase = x + (size_t)n * 409600 + tt * 400;

    for (int cc = 0; cc < 4; ++cc) {
        f32x4 acc[4][2];
        #pragma unroll
        for (int ml = 0; ml < 4; ++ml) {
            acc[ml][0] = (f32x4){0.f, 0.f, 0.f, 0.f};
            acc[ml][1] = (f32x4){0.f, 0.f, 0.f, 0.f};
        }

        __syncthreads();   // prev chunk done with xB
        const float* xc = xbase + cc * 100;
        #pragma unroll
        for (int it = 0; it < 7; ++it) {
            int j4 = tid + it * 256;
            if (j4 < 1600) {
                int c  = j4 / 25;
                int qq = (j4 - c * 25) * 4;
                float4 xv = *(const float4*)(xc + c * 6400 + qq);
                __bf16* dst = &xB[qq * 72 + c];
                dst[0]   = (__bf16)xv.x;
                dst[72]  = (__bf16)xv.y;
                dst[144] = (__bf16)xv.z;
                dst[216] = (__bf16)xv.w;
            }
        }
        __syncthreads();

        #pragma unroll
        for (int s = 0; s < 3; ++s) {
            // u MFMA: wave wv owns o-tile wv; 7 q-tiles of 16.
            // uL writes land in rows [wv*64, wv*64+64) — wave-private.
            #pragma unroll
            for (int qt = 0; qt < 7; ++qt) {
                const __bf16* bp = &xB[(qt * 16 + col) * 72 + quad * 8];
                bf16x8 b0 = *(const bf16x8*)bp;
                bf16x8 b1 = *(const bf16x8*)(bp + 32);
                f32x4 u = {0.f, 0.f, 0.f, 0.f};
                u = __builtin_amdgcn_mfma_f32_16x16x32_bf16(wd0[s], b0, u, 0, 0, 0);
                u = __builtin_amdgcn_mfma_f32_16x16x32_bf16(wd1[s], b1, u, 0, 0, 0);
                int q = qt * 16 + col;       // D col
                if (q < 100) {
                    int trel = q / 25, v = q - trel * 25;
                    int rowbase = ((wv * 16 + quad * 4) * 4 + trel) * 40 + v;
                    uL[rowbase]       = (__bf16)u[0];
                    uL[rowbase + 160] = (__bf16)u[1];
                    uL[rowbase + 320] = (__bf16)u[2];
                    uL[rowbase + 480] = (__bf16)u[3];
                }
            }
            // aggregation MFMA reads only rows [wv*64, wv*64+64) — same wave's
            // writes; same-wave ds ordering + compiler lgkmcnt make this safe
            // with NO barrier.
            #pragma unroll
            for (int ml = 0; ml < 4; ++ml) {
                int row = (wv * 4 + ml) * 16 + col;
                bf16x8 af = *(const bf16x8*)&uL[row * 40 + quad * 8];
                acc[ml][0] = __builtin_amdgcn_mfma_f32_16x16x32_bf16(af, aiH[s][0], acc[ml][0], 0, 0, 0);
                acc[ml][1] = __builtin_amdgcn_mfma_f32_16x16x32_bf16(af, aiH[s][1], acc[ml][1], 0, 0, 0);
                acc[ml][0] = __builtin_amdgcn_mfma_f32_16x16x32_bf16(af, aiL[s][0], acc[ml][0], 0, 0, 0);
                acc[ml][1] = __builtin_amdgcn_mfma_f32_16x16x32_bf16(af, aiL[s][1], acc[ml][1], 0, 0, 0);
            }
        }

        // epilogue for this chunk: t = tt*16 + cc*4 + r
        #pragma unroll
        for (int ml = 0; ml < 4; ++ml) {
            int o = (wv * 4 + ml) * 4 + quad;
            #pragma unroll
            for (int vt = 0; vt < 2; ++vt) {
                int v = vt * 16 + col;
                if (v < 25) {
                    const size_t base =
                        ((size_t)(n * 64 + o) * 256 + tt * 16 + cc * 4) * 25 + v;
                    float ms = 0.f;
                    #pragma unroll
                    for (int r = 0; r < 4; ++r) {
                        float val = scv[ml] * (acc[ml][vt][r] + bdsv[ml]) + btv[ml]
                                  + x[base + r * 25];
                        val = val > 0.f ? val : 0.f;
                        y1[base + r * 25] = val;
                        ms += val;
                    }
                    msum[ml][vt] += ms;
                }
            }
        }
    }

    // meanT partial sums (over this block's 16 t)
    #pragma unroll
    for (int ml = 0; ml < 4; ++ml) {
        int o = (wv * 4 + ml) * 4 + quad;
        #pragma unroll
        for (int vt = 0; vt < 2; ++vt) {
            int v = vt * 16 + col;
            if (v < 25)
                atomicAdd(&meanT[(n * 64 + o) * 25 + v], msum[ml][vt]);
        }
    }
}

// ---------------------------------------------------------------------------
// Kernel D: spatial SE gate.  g2p[n][v] = 1 + sigmoid(conv_V(meanT/T, Wsa)+bsa)
// ---------------------------------------------------------------------------
__global__ __launch_bounds__(256) void gcn_kD(const float* __restrict__ meanT,
                                              const float* __restrict__ Wsa,
                                              const float* __restrict__ bsa,
                                              float* __restrict__ g2p) {
    const int n = blockIdx.x;
    const int tid = threadIdx.x;
    __shared__ float sm[1600], wl[1600];
    for (int j = tid; j < 1600; j += 256) {
        sm[j] = meanT[n * 1600 + j] * (1.f / 256.f);
        wl[j] = Wsa[j];
    }
    __syncthreads();
    if (tid < 25) {
        float acc = bsa[0];
        for (int c = 0; c < 64; ++c) {
            #pragma unroll
            for (int k = 0; k < 25; ++k) {
                int j = tid + k - 12;
                if (j >= 0 && j < 25) acc += sm[c * 25 + j] * wl[c * 25 + k];
            }
        }
        g2p[n * 25 + tid] = 1.f + 1.f / (1.f + expf(-acc));
    }
}

// ---------------------------------------------------------------------------
// Kernel E: M2[n][c][t] = (1/V) sum_v y1 * g2p[n][v]  (float4 staging)
// ---------------------------------------------------------------------------
__global__ __launch_bounds__(256) void gcn_kE(const float* __restrict__ y1,
                                              const float* __restrict__ g2p,
                                              float* __restrict__ M2) {
    const int bid = blockIdx.x;     // n*64 + c
    const int n = bid >> 6;
    const int tid = threadIdx.x;
    __shared__ float yl[6400];
    __shared__ float g2l[25];
    const float4* yp = (const float4*)(y1 + (size_t)bid * 6400);
    float4* ylv = (float4*)yl;
    for (int j = tid; j < 1600; j += 256) ylv[j] = yp[j];
    if (tid < 25) g2l[tid] = g2p[n * 25 + tid];
    __syncthreads();
    float sum = 0.f;
    #pragma unroll
    for (int v = 0; v < 25; ++v) sum += yl[tid * 25 + v] * g2l[v];
    M2[bid * 256 + tid] = sum * 0.04f;
}

// ---------------------------------------------------------------------------
// Kernel FG (merge of kF+kG): per n, stage M2[n] in LDS once, then
//   g3[t] = 1 + sigmoid(conv_T(M2, Wta)+bta)
//   M3[c] = (1/T) sum_t M2[c][t]*g3[t];  MLP -> g4[c] = 1+sigmoid
// ---------------------------------------------------------------------------
__global__ __launch_bounds__(256) void gcn_kFG(const float* __restrict__ M2,
                                               const float* __restrict__ Wta,
                                               const float* __restrict__ bta,
                                               const float* __restrict__ W1,
                                               const float* __restrict__ b1,
                                               const float* __restrict__ W2,
                                               const float* __restrict__ b2,
                                               float* __restrict__ g3p,
                                               float* __restrict__ g4p) {
    const int n = blockIdx.x;
    const int tid = threadIdx.x;
    __shared__ float m2L[64 * 260];   // [c][t], pad 260
    __shared__ float wl[576];
    __shared__ float g3l[256], part[256], M3[64], h[32];

    for (int j = tid; j < 16384; j += 256) {
        int c = j >> 8, t = j & 255;
        m2L[c * 260 + t] = M2[(size_t)n * 16384 + j];
    }
    for (int j = tid; j < 576; j += 256) wl[j] = Wta[j];
    __syncthreads();

    // phase F: temporal conv (kernel 9, pad 4), t = tid
    {
        const int t = tid;
        float acc = bta[0];
        for (int c = 0; c < 64; ++c) {
            const float* mp = &m2L[c * 260];
            #pragma unroll
            for (int k = 0; k < 9; ++k) {
                int j = t + k - 4;
                if (j >= 0 && j < 256) acc += mp[j] * wl[c * 9 + k];
            }
        }
        float g3 = 1.f + 1.f / (1.f + expf(-acc));
        g3l[t] = g3;
        g3p[n * 256 + t] = g3;
    }
    __syncthreads();

    // phase G: channel SE
    {
        const int c = tid >> 2, q = tid & 3;
        float p = 0.f;
        const float* mp = &m2L[c * 260 + q * 64];
        #pragma unroll 16
        for (int j = 0; j < 64; ++j) p += mp[j] * g3l[q * 64 + j];
        part[tid] = p;
    }
    __syncthreads();
    if (tid < 64)
        M3[tid] = (part[tid * 4] + part[tid * 4 + 1] + part[tid * 4 + 2] +
                   part[tid * 4 + 3]) * (1.f / 256.f);
    __syncthreads();
    if (tid < 32) {
        float acc = b1[tid];
        #pragma unroll 16
        for (int cc = 0; cc < 64; ++cc) acc += W1[tid * 64 + cc] * M3[cc];
        h[tid] = acc > 0.f ? acc : 0.f;
    }
    __syncthreads();
    if (tid < 64) {
        float acc = b2[tid];
        #pragma unroll
        for (int j = 0; j < 32; ++j) acc += W2[tid * 32 + j] * h[j];
        g4p[n * 64 + tid] = 1.f + 1.f / (1.f + expf(-acc));
    }
}

// ---------------------------------------------------------------------------
// Kernel H: final gating, in place:  y = y1 * g2p[v] * g3p[t] * g4p[c]
// ---------------------------------------------------------------------------
__global__ __launch_bounds__(256) void gcn_kH(float* __restrict__ y,
                                              const float* __restrict__ g2p,
                                              const float* __restrict__ g3p,
                                              const float* __restrict__ g4p) {
    const int bid = blockIdx.x;  // n*64 + c
    const int n = bid >> 6;
    const int tid = threadIdx.x;
    __shared__ float g3l[256], g2l[25];
    g3l[tid] = g3p[n * 256 + tid];
    if (tid < 25) g2l[tid] = g2p[n * 25 + tid];
    const float g4 = g4p[bid];
    __syncthreads();
    float4* yp = (float4*)(y + (size_t)bid * 6400);
    for (int f = tid; f < 1600; f += 256) {
        float4 val = yp[f];
        float* vv = (float*)&val;
        const int base = f * 4;
        #pragma unroll
        for (int k = 0; k < 4; ++k) {
            int idx = base + k;
            int t = (int)(((unsigned long long)idx * 1374389535ull) >> 35);
            int v = idx - t * 25;
            vv[k] *= g2l[v] * g3l[t] * g4;
        }
        yp[f] = val;
    }
}

// ---------------------------------------------------------------------------
extern "C" void kernel_launch(void* const* d_in, const int* in_sizes, int n_in,
                              void* d_out, int out_size, void* d_ws, size_t ws_size,
                              hipStream_t stream) {
    const float* x     = (const float*)d_in[0];
    const float* PA    = (const float*)d_in[1];
    const float* alpha = (const float*)d_in[2];
    const float* Wa    = (const float*)d_in[3];
    const float* ba    = (const float*)d_in[4];
    const float* Wb    = (const float*)d_in[5];
    const float* bb    = (const float*)d_in[6];
    const float* Wd    = (const float*)d_in[7];
    const float* bd    = (const float*)d_in[8];
    const float* gamma = (const float*)d_in[9];
    const float* beta  = (const float*)d_in[10];
    const float* Wsa   = (const float*)d_in[11];
    const float* bsa   = (const float*)d_in[12];
    const float* Wta   = (const float*)d_in[13];
    const float* bta   = (const float*)d_in[14];
    const float* W1    = (const float*)d_in[15];
    const float* b1    = (const float*)d_in[16];
    const float* W2    = (const float*)d_in[17];
    const float* b2    = (const float*)d_in[18];

    float* out = (float*)d_out;
    float* ws  = (float*)d_ws;

    // workspace layout (floats)
    float*  Pws   = ws;                        // 120000  (zeroed; kA atomics)
    float*  meanT = ws + 120000;               // 102400  (zeroed; kC atomics)
    __bf16* aiF   = (__bf16*)(ws + 222400);    // 393216 bf16 = 196608 f (zeroed pads)
    float*  M2    = ws + 419008;               // 4194304
    float*  g2p   = ws + 4613312;              // 1600
    float*  g3p   = ws + 4614912;              // 16384
    float*  g4p   = ws + 4631296;              // 4096

    hipMemsetAsync(ws, 0, 222400 * sizeof(float), stream);   // Pws + meanT
    hipMemsetAsync(aiF, 0, 786432, stream);                  // aiF (incl. pads)

    gcn_kA<<<1024, 256, 0, stream>>>(x, Wa, ba, Wb, bb, Pws);
    gcn_kB<<<469, 256, 0, stream>>>(Pws, PA, alpha, aiF);
    gcn_kC<<<1024, 256, 0, stream>>>(x, aiF, Wd, bd, gamma, beta, out, meanT);
    gcn_kD<<<64, 256, 0, stream>>>(meanT, Wsa, bsa, g2p);
    gcn_kE<<<4096, 256, 0, stream>>>(out, g2p, M2);
    gcn_kFG<<<64, 256, 0, stream>>>(M2, Wta, bta, W1, b1, W2, b2, g3p, g4p);
    gcn_kH<<<4096, 256, 0, stream>>>(out, g2p, g3p, g4p);
}